// Round 1
// baseline (3629.134 us; speedup 1.0000x reference)
//
#include <hip/hip_runtime.h>

#define NN 2
#define KC 32
#define TT 100
#define HH 64
#define WW 64
#define HWSZ (HH*WW)            // 4096
#define RB 4                    // row-blocks per channel image
#define RROWS 16                // rows per block
#define HALO 14
#define BROWS (RROWS + 2*HALO)  // 44
#define SW 65                   // LDS row stride (pad +1: kills column-access bank conflicts)
#define WGS_PER_DOMAIN (KC*RB)  // 128 wgs per batch (independent barrier domains)
#define NWG (NN*WGS_PER_DOMAIN) // 256

__device__ __forceinline__ float wave_incl_scan(float v, int lane) {
  #pragma unroll
  for (int d = 1; d < 64; d <<= 1) {
    float o = __shfl_up(v, (unsigned)d, 64);
    if (lane >= d) v += o;
  }
  return v;
}

__global__ void __launch_bounds__(256, 1) ring_kernel(
    const float* __restrict__ inbound, const float* __restrict__ Wf,
    const float* __restrict__ bf, const float* __restrict__ Ws,
    const float* __restrict__ bs, float* __restrict__ out,
    unsigned* __restrict__ ctrs)
{
  __shared__ float I[BROWS*SW];   // 44*65*4 = 11.4 KB

  const int b    = blockIdx.x;
  const int n    = b >> 7;            // batch  (barrier domain)
  const int c    = (b >> 2) & (KC-1); // owned channel
  const int rb   = b & (RB-1);        // row block
  const int tid  = threadIdx.x;
  const int lane = tid & 63;
  const int wave = tid >> 6;
  const int r0   = rb * RROWS;

  // surround kernel structure: constant inh + center 9x9 at exc (read values from input)
  const float inh = Ws[0];
  const float exc = Ws[14*29 + 14];
  const float w9  = exc - inh;

  float wf[KC];
  #pragma unroll
  for (int i = 0; i < KC; ++i) wf[i] = Wf[c*KC + i];   // c uniform -> scalar loads
  const float bsum = bf[c] + bs[c];

  // own 4 pixels (float4-aligned) inside the channel image
  const int off = rb*(RROWS*WW) + tid*4;
  float4 dr = *(const float4*)(inbound + (size_t)(n*KC + c)*HWSZ + off);
  const float base0 = 0.5f*dr.x + bsum;
  const float base1 = 0.5f*dr.y + bsum;
  const float base2 = 0.5f*dr.z + bsum;
  const float base3 = 0.5f*dr.w + bsum;

  const int rl = tid >> 4;        // local row 0..15
  const int w0 = (tid & 15) * 4;  // col of first owned px
  const int br = rl + HALO;       // block-row of own px in I

  unsigned* ctr = ctrs + n*32;    // one cacheline-separated counter per batch

  for (int t = 0; t < TT; ++t) {
    const float* Xprev = out + (size_t)((n*TT + (t-1))*KC)*HWSZ; // deref'd only when t>0

    // Phase A: stage own-channel halo block (zero-pad outside image; zeros at t==0)
    {
      const float* Xc = Xprev + (size_t)c*HWSZ;
      for (int l = tid; l < BROWS*WW; l += 256) {
        int row = l >> 6, w = l & 63;
        int g = r0 - HALO + row;
        float v = 0.f;
        if (t > 0 && g >= 0 && g < HH) v = Xc[g*WW + w];
        I[row*SW + w] = v;
      }
    }
    __syncthreads();

    // Phase A2: horizontal inclusive prefix per row (wave shuffle scan, width 64)
    #pragma unroll
    for (int k = 0; k < 11; ++k) {
      int row = wave*11 + k;
      float v = I[row*SW + lane];
      v = wave_incl_scan(v, lane);
      I[row*SW + lane] = v;
    }
    __syncthreads();

    // Phase A3: vertical prefix per column -> 2D integral image
    #pragma unroll
    for (int k = 0; k < 16; ++k) {
      int col = wave*16 + k;
      float v = (lane < BROWS) ? I[lane*SW + col] : 0.f;
      v = wave_incl_scan(v, lane);
      if (lane < BROWS) I[lane*SW + col] = v;
    }
    __syncthreads();

    // Phase B: box fields for own 4 px (8 corner reads per px)
    float s[4];
    #pragma unroll
    for (int j = 0; j < 4; ++j) {
      int w = w0 + j;
      int hi  = br + 14, lo  = br - 15;
      int whi = (w + 14 > 63) ? 63 : (w + 14);
      int wlo = w - 15;
      float b29 = I[hi*SW + whi];
      if (wlo >= 0) b29 -= I[hi*SW + wlo];
      if (lo  >= 0) { b29 -= I[lo*SW + whi]; if (wlo >= 0) b29 += I[lo*SW + wlo]; }
      int hi2  = br + 4, lo2 = br - 5;        // lo2 >= 9 always: no guard needed
      int whi2 = (w + 4 > 63) ? 63 : (w + 4);
      int wlo2 = w - 5;
      float b9 = I[hi2*SW + whi2];
      if (wlo2 >= 0) b9 -= I[hi2*SW + wlo2];
      b9 -= I[lo2*SW + whi2];
      if (wlo2 >= 0) b9 += I[lo2*SW + wlo2];
      s[j] = inh*b29 + w9*b9;
    }
    float s0 = base0 + s[0], s1 = base1 + s[1], s2 = base2 + s[2], s3 = base3 + s[3];

    // Phase C: channel matvec from slice t-1 (coalesced float4 across wave)
    float4 xold = make_float4(0.f, 0.f, 0.f, 0.f);
    if (t > 0) {
      const float* Xp = Xprev + off;
      #pragma unroll 8
      for (int i = 0; i < KC; ++i) {
        float4 x = *(const float4*)(Xp + (size_t)i*HWSZ);
        s0 += wf[i]*x.x; s1 += wf[i]*x.y; s2 += wf[i]*x.z; s3 += wf[i]*x.w;
        if (i == c) xold = x;   // own channel doubles as the decay input
      }
    }

    // Phase D: update + store to slice t (state history lives in d_out)
    float4 xn;
    xn.x = 0.8f*xold.x + 0.2f*fmaxf(s0, 0.f);
    xn.y = 0.8f*xold.y + 0.2f*fmaxf(s1, 0.f);
    xn.z = 0.8f*xold.z + 0.2f*fmaxf(s2, 0.f);
    xn.w = 0.8f*xold.w + 0.2f*fmaxf(s3, 0.f);
    *(float4*)(out + (size_t)((n*TT + t)*KC + c)*HWSZ + off) = xn;

    // per-batch grid barrier (monotone epoch counter; no sense reversal, no ABA)
    if (t < TT-1) {
      __syncthreads();
      if (tid == 0) {
        __threadfence();
        __hip_atomic_fetch_add(ctr, 1u, __ATOMIC_ACQ_REL, __HIP_MEMORY_SCOPE_AGENT);
        unsigned target = (unsigned)(WGS_PER_DOMAIN*(t+1));
        while (__hip_atomic_load(ctr, __ATOMIC_ACQUIRE, __HIP_MEMORY_SCOPE_AGENT) < target) {
          __builtin_amdgcn_s_sleep(2);
        }
        __threadfence();
      }
      __syncthreads();
    }
  }
}

extern "C" void kernel_launch(void* const* d_in, const int* in_sizes, int n_in,
                              void* d_out, int out_size, void* d_ws, size_t ws_size,
                              hipStream_t stream) {
  const float* inbound = (const float*)d_in[0];
  const float* Wf      = (const float*)d_in[1];
  const float* bf      = (const float*)d_in[2];
  const float* Ws      = (const float*)d_in[3];
  const float* bs      = (const float*)d_in[4];
  float* out = (float*)d_out;
  unsigned* ctrs = (unsigned*)d_ws;

  // barrier counters must start at 0 every replay (ws is re-poisoned to 0xAA)
  hipMemsetAsync(d_ws, 0, 256, stream);

  void* args[] = {(void*)&inbound, (void*)&Wf, (void*)&bf, (void*)&Ws,
                  (void*)&bs, (void*)&out, (void*)&ctrs};
  hipLaunchCooperativeKernel((void*)ring_kernel, dim3(NWG), dim3(256),
                             args, 0, stream);
}

// Round 2
// 2320.216 us; speedup vs baseline: 1.5641x; 1.5641x over previous
//
#include <hip/hip_runtime.h>

#define NN 2
#define KC 32
#define TT 100
#define HH 64
#define WW 64
#define HWSZ (HH*WW)            // 4096
#define RB 4                    // row-blocks per channel image
#define RROWS 16                // rows per block
#define HALO 14
#define BROWS (RROWS + 2*HALO)  // 44
#define SW 65                   // LDS row stride (pad +1: kills column-access bank conflicts)
#define WGS_PER_DOMAIN (KC*RB)  // 128 wgs per batch
#define NWG (NN*WGS_PER_DOMAIN) // 256
#define FLAG_STRIDE 16          // uints per flag slot = 64 B (own cacheline)

__device__ __forceinline__ float wave_incl_scan(float v, int lane) {
  #pragma unroll
  for (int d = 1; d < 64; d <<= 1) {
    float o = __shfl_up(v, (unsigned)d, 64);
    if (lane >= d) v += o;
  }
  return v;
}

__global__ void __launch_bounds__(256, 1) ring_kernel(
    const float* __restrict__ inbound, const float* __restrict__ Wf,
    const float* __restrict__ bf, const float* __restrict__ Ws,
    const float* __restrict__ bs, float* __restrict__ out,
    unsigned* __restrict__ flags)
{
  __shared__ float I[BROWS*SW];   // 44*65*4 = 11.4 KB

  const int b    = blockIdx.x;
  const int n    = b >> 7;            // batch
  const int c    = (b >> 2) & (KC-1); // owned channel
  const int rb   = b & (RB-1);        // row block
  const int tid  = threadIdx.x;
  const int lane = tid & 63;
  const int wave = tid >> 6;
  const int r0   = rb * RROWS;

  // surround kernel structure: constant inh + center 9x9 at exc
  const float inh = Ws[0];
  const float exc = Ws[14*29 + 14];
  const float w9  = exc - inh;

  float wf[KC];
  #pragma unroll
  for (int i = 0; i < KC; ++i) wf[i] = Wf[c*KC + i];   // c uniform -> scalar loads
  const float bsum = bf[c] + bs[c];

  // own 4 pixels (float4-aligned) inside the channel image
  const int off = rb*(RROWS*WW) + tid*4;
  float4 dr = *(const float4*)(inbound + (size_t)(n*KC + c)*HWSZ + off);
  const float base0 = 0.5f*dr.x + bsum;
  const float base1 = 0.5f*dr.y + bsum;
  const float base2 = 0.5f*dr.z + bsum;
  const float base3 = 0.5f*dr.w + bsum;

  const int rl = tid >> 4;        // local row 0..15
  const int w0 = (tid & 15) * 4;  // col of first owned px
  const int br = rl + HALO;       // block-row of own px in I

  // ---- distributed epoch flags -------------------------------------------
  // flag[(n,c,rb)] == s  means  "this wg has finished WRITING slice s-1".
  // At step t a consumer needs slice t-1  =>  wait flag >= t.
  // Dependency set of wg (n,c,rb): all 32 channels at same rb (matvec) +
  // same channel rb-1 / rb+1 (conv halo).  34 flags, one poller thread each.
  const int ownf = ((n<<7) | (c<<2) | rb) * FLAG_STRIDE;
  int pollf = ownf;                       // default: self (always satisfied)
  if (tid < 32)               pollf = ((n<<7) | (tid<<2) | rb)     * FLAG_STRIDE;
  else if (tid == 32 && rb>0) pollf = ((n<<7) | (c<<2) | (rb-1))   * FLAG_STRIDE;
  else if (tid == 33 && rb<RB-1) pollf = ((n<<7) | (c<<2) | (rb+1))* FLAG_STRIDE;
  unsigned* pollp = flags + pollf;
  unsigned* ownp  = flags + ownf;

  for (int t = 0; t < TT; ++t) {
    const float* Xprev = out + (size_t)((n*TT + (t-1))*KC)*HWSZ; // deref'd only when t>0

    // ---- wait for the 34 producers of slice t-1 (relaxed poll, no L2 inv) --
    if (t > 0) {
      if (tid < 34) {
        const unsigned tgt = (unsigned)t;
        while (__hip_atomic_load(pollp, __ATOMIC_RELAXED, __HIP_MEMORY_SCOPE_AGENT) < tgt) {
          __builtin_amdgcn_s_sleep(1);
        }
      }
      __syncthreads();
      // single acquire per wg per step: makes producers' flushed data visible
      __builtin_amdgcn_fence(__ATOMIC_ACQUIRE, "agent");
    }

    // Phase A: stage own-channel halo block (zero-pad outside image)
    {
      const float* Xc = Xprev + (size_t)c*HWSZ;
      for (int l = tid; l < BROWS*WW; l += 256) {
        int row = l >> 6, w = l & 63;
        int g = r0 - HALO + row;
        float v = 0.f;
        if (t > 0 && g >= 0 && g < HH) v = Xc[g*WW + w];
        I[row*SW + w] = v;
      }
    }
    __syncthreads();

    // Phase A2: horizontal inclusive prefix per row
    #pragma unroll
    for (int k = 0; k < 11; ++k) {
      int row = wave*11 + k;
      float v = I[row*SW + lane];
      v = wave_incl_scan(v, lane);
      I[row*SW + lane] = v;
    }
    __syncthreads();

    // Phase A3: vertical prefix per column -> 2D integral image
    #pragma unroll
    for (int k = 0; k < 16; ++k) {
      int col = wave*16 + k;
      float v = (lane < BROWS) ? I[lane*SW + col] : 0.f;
      v = wave_incl_scan(v, lane);
      if (lane < BROWS) I[lane*SW + col] = v;
    }
    __syncthreads();

    // Phase B: box fields for own 4 px (8 corner reads per px)
    float s[4];
    #pragma unroll
    for (int j = 0; j < 4; ++j) {
      int w = w0 + j;
      int hi  = br + 14, lo  = br - 15;
      int whi = (w + 14 > 63) ? 63 : (w + 14);
      int wlo = w - 15;
      float b29 = I[hi*SW + whi];
      if (wlo >= 0) b29 -= I[hi*SW + wlo];
      if (lo  >= 0) { b29 -= I[lo*SW + whi]; if (wlo >= 0) b29 += I[lo*SW + wlo]; }
      int hi2  = br + 4, lo2 = br - 5;
      int whi2 = (w + 4 > 63) ? 63 : (w + 4);
      int wlo2 = w - 5;
      float b9 = I[hi2*SW + whi2];
      if (wlo2 >= 0) b9 -= I[hi2*SW + wlo2];
      b9 -= I[lo2*SW + whi2];
      if (wlo2 >= 0) b9 += I[lo2*SW + wlo2];
      s[j] = inh*b29 + w9*b9;
    }
    float s0 = base0 + s[0], s1 = base1 + s[1], s2 = base2 + s[2], s3 = base3 + s[3];

    // Phase C: channel matvec from slice t-1 (coalesced float4 across wave)
    float4 xold = make_float4(0.f, 0.f, 0.f, 0.f);
    if (t > 0) {
      const float* Xp = Xprev + off;
      #pragma unroll 8
      for (int i = 0; i < KC; ++i) {
        float4 x = *(const float4*)(Xp + (size_t)i*HWSZ);
        s0 += wf[i]*x.x; s1 += wf[i]*x.y; s2 += wf[i]*x.z; s3 += wf[i]*x.w;
        if (i == c) xold = x;   // own channel doubles as the decay input
      }
    }

    // Phase D: update + store to slice t
    float4 xn;
    xn.x = 0.8f*xold.x + 0.2f*fmaxf(s0, 0.f);
    xn.y = 0.8f*xold.y + 0.2f*fmaxf(s1, 0.f);
    xn.z = 0.8f*xold.z + 0.2f*fmaxf(s2, 0.f);
    xn.w = 0.8f*xold.w + 0.2f*fmaxf(s3, 0.f);
    *(float4*)(out + (size_t)((n*TT + t)*KC + c)*HWSZ + off) = xn;

    // ---- publish: slice t written ------------------------------------------
    if (t < TT-1) {
      __syncthreads();                 // drains vmcnt: all wg stores are in L2
      if (tid == 0) {
        __builtin_amdgcn_fence(__ATOMIC_RELEASE, "agent");  // L2 writeback -> LLC
        __hip_atomic_store(ownp, (unsigned)(t+1), __ATOMIC_RELAXED,
                           __HIP_MEMORY_SCOPE_AGENT);
      }
      // no second __syncthreads needed: consumers gate on the flags, and our
      // own next-step Phase A reads our own writes (program order) + flags.
      __syncthreads();
    }
  }
}

extern "C" void kernel_launch(void* const* d_in, const int* in_sizes, int n_in,
                              void* d_out, int out_size, void* d_ws, size_t ws_size,
                              hipStream_t stream) {
  const float* inbound = (const float*)d_in[0];
  const float* Wf      = (const float*)d_in[1];
  const float* bf      = (const float*)d_in[2];
  const float* Ws      = (const float*)d_in[3];
  const float* bs      = (const float*)d_in[4];
  float* out = (float*)d_out;
  unsigned* flags = (unsigned*)d_ws;

  // flags must start at 0 every replay (ws is re-poisoned to 0xAA)
  hipMemsetAsync(d_ws, 0, NWG*FLAG_STRIDE*sizeof(unsigned), stream);

  void* args[] = {(void*)&inbound, (void*)&Wf, (void*)&bf, (void*)&Ws,
                  (void*)&bs, (void*)&out, (void*)&flags};
  hipLaunchCooperativeKernel((void*)ring_kernel, dim3(NWG), dim3(256),
                             args, 0, stream);
}

// Round 4
// 1014.282 us; speedup vs baseline: 3.5780x; 2.2875x over previous
//
#include <hip/hip_runtime.h>

#define NN 2
#define KC 32
#define TT 100
#define HH 64
#define WW 64
#define HWSZ (HH*WW)            // 4096
#define RB 4                    // row-blocks per channel image
#define RROWS 16                // rows per block
#define HALO 14
#define BROWS (RROWS + 2*HALO)  // 44
#define SW 65                   // LDS row stride (65%32: column access conflict-free)
#define NWG (NN*KC*RB)          // 256
#define FLAG_STRIDE 16          // 64 B per flag slot

typedef float fx4 __attribute__((ext_vector_type(4)));

// ---- coherent state traffic: sc0 sc1 = bypass L1+L2, served at the
// memory-side Infinity Cache (always coherent).  No buffer_inv/wbl2 needed.
#define GLD8(x0,x1,x2,x3,x4,x5,x6,x7,p0,p1,p2,p3,p4,p5,p6,p7) \
  asm volatile( \
    "global_load_dwordx4 %0, %8, off sc0 sc1\n\t" \
    "global_load_dwordx4 %1, %9, off sc0 sc1\n\t" \
    "global_load_dwordx4 %2, %10, off sc0 sc1\n\t" \
    "global_load_dwordx4 %3, %11, off sc0 sc1\n\t" \
    "global_load_dwordx4 %4, %12, off sc0 sc1\n\t" \
    "global_load_dwordx4 %5, %13, off sc0 sc1\n\t" \
    "global_load_dwordx4 %6, %14, off sc0 sc1\n\t" \
    "global_load_dwordx4 %7, %15, off sc0 sc1" \
    : "=&v"(x0),"=&v"(x1),"=&v"(x2),"=&v"(x3), \
      "=&v"(x4),"=&v"(x5),"=&v"(x6),"=&v"(x7) \
    : "v"(p0),"v"(p1),"v"(p2),"v"(p3),"v"(p4),"v"(p5),"v"(p6),"v"(p7) \
    : "memory")

#define GLD3(x0,x1,x2,p0,p1,p2) \
  asm volatile( \
    "global_load_dwordx4 %0, %3, off sc0 sc1\n\t" \
    "global_load_dwordx4 %1, %4, off sc0 sc1\n\t" \
    "global_load_dwordx4 %2, %5, off sc0 sc1" \
    : "=&v"(x0),"=&v"(x1),"=&v"(x2) \
    : "v"(p0),"v"(p1),"v"(p2) : "memory")

// waitcnt that TIES the loaded registers: consumers of x* are ordered after it
#define VWAIT8(x0,x1,x2,x3,x4,x5,x6,x7) \
  asm volatile("s_waitcnt vmcnt(0)" \
    : "+v"(x0),"+v"(x1),"+v"(x2),"+v"(x3),"+v"(x4),"+v"(x5),"+v"(x6),"+v"(x7) \
    :: "memory")
#define VWAIT3(x0,x1,x2) \
  asm volatile("s_waitcnt vmcnt(0)" : "+v"(x0),"+v"(x1),"+v"(x2) :: "memory")

#define GST4(p, v) \
  asm volatile("global_store_dwordx4 %0, %1, off sc0 sc1" :: "v"(p), "v"(v) : "memory")

// raw barriers: LDS-only drain (keeps global prefetch in flight), or full drain
#define BAR_LDS()  asm volatile("s_waitcnt lgkmcnt(0)\n\ts_barrier" ::: "memory")
#define BAR_ONLY() asm volatile("s_barrier" ::: "memory")
#define BAR_FULL() asm volatile("s_waitcnt vmcnt(0) lgkmcnt(0)\n\ts_barrier" ::: "memory")

#define ACC(V, ch) do { const float w_ = wf[(ch)]; \
    s0 += w_*(V)[0]; s1 += w_*(V)[1]; s2 += w_*(V)[2]; s3 += w_*(V)[3]; \
    if ((ch) == c) xold = (V); } while (0)

__device__ __forceinline__ float wave_incl_scan(float v, int lane) {
  #pragma unroll
  for (int d = 1; d < 64; d <<= 1) {
    float o = __shfl_up(v, (unsigned)d, 64);
    if (lane >= d) v += o;
  }
  return v;
}

__global__ void __launch_bounds__(256, 1) ring_kernel(
    const float* __restrict__ inbound, const float* __restrict__ Wf,
    const float* __restrict__ bf, const float* __restrict__ Ws,
    const float* __restrict__ bs, float* __restrict__ out,
    unsigned* __restrict__ flags)
{
  __shared__ float I[BROWS*SW];   // 11.4 KB

  const int b    = blockIdx.x;
  const int n    = b >> 7;
  const int c    = (b >> 2) & (KC-1);
  const int rb   = b & (RB-1);
  const int tid  = threadIdx.x;
  const int lane = tid & 63;
  const int wave = tid >> 6;
  const int r0   = rb * RROWS;

  const float inh = Ws[0];
  const float exc = Ws[14*29 + 14];
  const float w9  = exc - inh;

  float wf[KC];
  #pragma unroll
  for (int i = 0; i < KC; ++i) wf[i] = Wf[c*KC + i];
  const float bsum = bf[c] + bs[c];

  const int off = rb*(RROWS*WW) + tid*4;
  const float* drp = inbound + (size_t)(n*KC + c)*HWSZ + off;
  const float base0 = 0.5f*drp[0] + bsum;
  const float base1 = 0.5f*drp[1] + bsum;
  const float base2 = 0.5f*drp[2] + bsum;
  const float base3 = 0.5f*drp[3] + bsum;

  const int rl = tid >> 4;
  const int w0 = (tid & 15) * 4;
  const int br = rl + HALO;

  // halo staging: 44 rows x 16 float4-chunks = 704 chunks; thread does <=3
  int  hlofs[3], hgofs[3];
  bool hval[3];
  #pragma unroll
  for (int q = 0; q < 3; ++q) {
    int id  = tid + q*256; if (id > 703) id = 703;
    int row = id >> 4;
    int c4  = (id & 15) * 4;
    int g   = r0 - HALO + row;
    hval[q]  = (g >= 0 && g < HH);
    int gc   = g < 0 ? 0 : (g > HH-1 ? HH-1 : g);
    hgofs[q] = gc*WW + c4;      // float offset inside a channel slice
    hlofs[q] = row*SW + c4;     // float offset inside LDS tile
  }

  // flags: flag[(n,c,rb)] == s  <=>  that wg finished writing slice s-1
  const int ownf = ((n<<7) | (c<<2) | rb) * FLAG_STRIDE;
  int pollf = ownf;
  if (tid < 32)                  pollf = ((n<<7) | (tid<<2) | rb)    * FLAG_STRIDE;
  else if (tid == 32 && rb>0)    pollf = ((n<<7) | (c<<2) | (rb-1))  * FLAG_STRIDE;
  else if (tid == 33 && rb<RB-1) pollf = ((n<<7) | (c<<2) | (rb+1))  * FLAG_STRIDE;
  unsigned* pollp = flags + pollf;
  unsigned* ownp  = flags + ownf;

  for (int t = 0; t < TT; ++t) {
    const float* Xprev = out + (size_t)((n*TT + (t-1))*KC)*HWSZ;

    fx4 A0,A1,A2v,A3v,A4,A5,A6,A7;   // channel batches
    fx4 B0,B1,B2,B3,B4,B5,B6,B7;
    fx4 h0,h1,h2;

    if (t > 0) {
      // wait for the 34 producers of slice t-1 (relaxed poll: no cache ops)
      if (tid < 34) {
        const unsigned tgt = (unsigned)t;
        while (__hip_atomic_load(pollp, __ATOMIC_RELAXED, __HIP_MEMORY_SCOPE_AGENT) < tgt) {
          __builtin_amdgcn_s_sleep(1);
        }
      }
      BAR_ONLY();

      // issue halo + first 16 channel loads
      const float* Xc = Xprev + (size_t)c*HWSZ;
      GLD3(h0,h1,h2, (const fx4*)(Xc+hgofs[0]),
                     (const fx4*)(Xc+hgofs[1]),
                     (const fx4*)(Xc+hgofs[2]));
      const float* Xp = Xprev + off;
      GLD8(A0,A1,A2v,A3v,A4,A5,A6,A7,
           (const fx4*)(Xp+(size_t)0*HWSZ),(const fx4*)(Xp+(size_t)1*HWSZ),
           (const fx4*)(Xp+(size_t)2*HWSZ),(const fx4*)(Xp+(size_t)3*HWSZ),
           (const fx4*)(Xp+(size_t)4*HWSZ),(const fx4*)(Xp+(size_t)5*HWSZ),
           (const fx4*)(Xp+(size_t)6*HWSZ),(const fx4*)(Xp+(size_t)7*HWSZ));
      GLD8(B0,B1,B2,B3,B4,B5,B6,B7,
           (const fx4*)(Xp+(size_t)8*HWSZ),(const fx4*)(Xp+(size_t)9*HWSZ),
           (const fx4*)(Xp+(size_t)10*HWSZ),(const fx4*)(Xp+(size_t)11*HWSZ),
           (const fx4*)(Xp+(size_t)12*HWSZ),(const fx4*)(Xp+(size_t)13*HWSZ),
           (const fx4*)(Xp+(size_t)14*HWSZ),(const fx4*)(Xp+(size_t)15*HWSZ));

      VWAIT3(h0,h1,h2);
      if (!hval[0]) h0 = fx4{0.f,0.f,0.f,0.f};
      if (!hval[1]) h1 = fx4{0.f,0.f,0.f,0.f};
      if (!hval[2]) h2 = fx4{0.f,0.f,0.f,0.f};
      I[hlofs[0]+0]=h0[0]; I[hlofs[0]+1]=h0[1]; I[hlofs[0]+2]=h0[2]; I[hlofs[0]+3]=h0[3];
      I[hlofs[1]+0]=h1[0]; I[hlofs[1]+1]=h1[1]; I[hlofs[1]+2]=h1[2]; I[hlofs[1]+3]=h1[3];
      I[hlofs[2]+0]=h2[0]; I[hlofs[2]+1]=h2[1]; I[hlofs[2]+2]=h2[2]; I[hlofs[2]+3]=h2[3];
    } else {
      for (int l = tid; l < BROWS*WW; l += 256) I[(l>>6)*SW + (l&63)] = 0.f;
    }
    BAR_LDS();

    // horizontal inclusive prefix per row
    #pragma unroll
    for (int k = 0; k < 11; ++k) {
      int row = wave*11 + k;
      float v = I[row*SW + lane];
      v = wave_incl_scan(v, lane);
      I[row*SW + lane] = v;
    }
    BAR_LDS();

    // vertical prefix per column -> 2D integral image
    #pragma unroll
    for (int k = 0; k < 16; ++k) {
      int col = wave*16 + k;
      float v = (lane < BROWS) ? I[lane*SW + col] : 0.f;
      v = wave_incl_scan(v, lane);
      if (lane < BROWS) I[lane*SW + col] = v;
    }
    BAR_LDS();

    // box fields for own 4 px
    float s[4];
    #pragma unroll
    for (int j = 0; j < 4; ++j) {
      int w = w0 + j;
      int hi  = br + 14, lo  = br - 15;
      int whi = (w + 14 > 63) ? 63 : (w + 14);
      int wlo = w - 15;
      float b29 = I[hi*SW + whi];
      if (wlo >= 0) b29 -= I[hi*SW + wlo];
      if (lo  >= 0) { b29 -= I[lo*SW + whi]; if (wlo >= 0) b29 += I[lo*SW + wlo]; }
      int hi2  = br + 4, lo2 = br - 5;
      int whi2 = (w + 4 > 63) ? 63 : (w + 4);
      int wlo2 = w - 5;
      float b9 = I[hi2*SW + whi2];
      if (wlo2 >= 0) b9 -= I[hi2*SW + wlo2];
      b9 -= I[lo2*SW + whi2];
      if (wlo2 >= 0) b9 += I[lo2*SW + wlo2];
      s[j] = inh*b29 + w9*b9;
    }
    float s0 = base0 + s[0], s1 = base1 + s[1], s2 = base2 + s[2], s3 = base3 + s[3];

    // channel matvec (coherent loads; first 16 in flight since step start)
    fx4 xold = fx4{0.f,0.f,0.f,0.f};
    if (t > 0) {
      const float* Xp = Xprev + off;
      VWAIT8(A0,A1,A2v,A3v,A4,A5,A6,A7);
      VWAIT8(B0,B1,B2,B3,B4,B5,B6,B7);
      ACC(A0,0); ACC(A1,1); ACC(A2v,2); ACC(A3v,3);
      ACC(A4,4); ACC(A5,5); ACC(A6,6);  ACC(A7,7);
      GLD8(A0,A1,A2v,A3v,A4,A5,A6,A7,
           (const fx4*)(Xp+(size_t)16*HWSZ),(const fx4*)(Xp+(size_t)17*HWSZ),
           (const fx4*)(Xp+(size_t)18*HWSZ),(const fx4*)(Xp+(size_t)19*HWSZ),
           (const fx4*)(Xp+(size_t)20*HWSZ),(const fx4*)(Xp+(size_t)21*HWSZ),
           (const fx4*)(Xp+(size_t)22*HWSZ),(const fx4*)(Xp+(size_t)23*HWSZ));
      ACC(B0,8);  ACC(B1,9);  ACC(B2,10); ACC(B3,11);
      ACC(B4,12); ACC(B5,13); ACC(B6,14); ACC(B7,15);
      GLD8(B0,B1,B2,B3,B4,B5,B6,B7,
           (const fx4*)(Xp+(size_t)24*HWSZ),(const fx4*)(Xp+(size_t)25*HWSZ),
           (const fx4*)(Xp+(size_t)26*HWSZ),(const fx4*)(Xp+(size_t)27*HWSZ),
           (const fx4*)(Xp+(size_t)28*HWSZ),(const fx4*)(Xp+(size_t)29*HWSZ),
           (const fx4*)(Xp+(size_t)30*HWSZ),(const fx4*)(Xp+(size_t)31*HWSZ));
      VWAIT8(A0,A1,A2v,A3v,A4,A5,A6,A7);
      VWAIT8(B0,B1,B2,B3,B4,B5,B6,B7);
      ACC(A0,16); ACC(A1,17); ACC(A2v,18); ACC(A3v,19);
      ACC(A4,20); ACC(A5,21); ACC(A6,22);  ACC(A7,23);
      ACC(B0,24); ACC(B1,25); ACC(B2,26);  ACC(B3,27);
      ACC(B4,28); ACC(B5,29); ACC(B6,30);  ACC(B7,31);
    }

    // update + coherent store to slice t
    fx4 xn;
    xn[0] = 0.8f*xold[0] + 0.2f*fmaxf(s0, 0.f);
    xn[1] = 0.8f*xold[1] + 0.2f*fmaxf(s1, 0.f);
    xn[2] = 0.8f*xold[2] + 0.2f*fmaxf(s2, 0.f);
    xn[3] = 0.8f*xold[3] + 0.2f*fmaxf(s3, 0.f);
    float* po = out + (size_t)((n*TT + t)*KC + c)*HWSZ + off;
    GST4((fx4*)po, xn);

    // publish: every wave drains its stores to LLC, then one relaxed flag store
    if (t < TT-1) {
      BAR_FULL();
      if (tid == 0) {
        __hip_atomic_store(ownp, (unsigned)(t+1), __ATOMIC_RELAXED,
                           __HIP_MEMORY_SCOPE_AGENT);
      }
    }
  }
}

extern "C" void kernel_launch(void* const* d_in, const int* in_sizes, int n_in,
                              void* d_out, int out_size, void* d_ws, size_t ws_size,
                              hipStream_t stream) {
  const float* inbound = (const float*)d_in[0];
  const float* Wf      = (const float*)d_in[1];
  const float* bf      = (const float*)d_in[2];
  const float* Ws      = (const float*)d_in[3];
  const float* bs      = (const float*)d_in[4];
  float* out = (float*)d_out;
  unsigned* flags = (unsigned*)d_ws;

  hipMemsetAsync(d_ws, 0, NWG*FLAG_STRIDE*sizeof(unsigned), stream);

  void* args[] = {(void*)&inbound, (void*)&Wf, (void*)&bf, (void*)&Ws,
                  (void*)&bs, (void*)&out, (void*)&flags};
  hipLaunchCooperativeKernel((void*)ring_kernel, dim3(NWG), dim3(256),
                             args, 0, stream);
}

// Round 6
// 990.431 us; speedup vs baseline: 3.6642x; 1.0241x over previous
//
#include <hip/hip_runtime.h>

#define NN 2
#define KC 32
#define G  4                    // output channels per wg (one per wave)
#define CG (KC/G)               // 8 channel-groups
#define TT 100
#define HH 64
#define WW 64
#define HWSZ (HH*WW)            // 4096
#define RB 4                    // row-blocks per channel image
#define RROWS 16
#define HALO 14
#define BROWS (RROWS + 2*HALO)  // 44
#define SW 65                   // LDS row stride (65%32==1: serial col/row walks conflict-free)
#define TSZ (BROWS*SW)          // 2860 floats per tile
#define NWG (NN*CG*RB)          // 64
#define FLAG_STRIDE 16          // 64 B per flag slot

typedef float fx4 __attribute__((ext_vector_type(4)));

// coherent (LLC-point) traffic: sc0 sc1 bypasses L1+L2 -> always coherent.
// HARD RULE (R5 lesson): never keep more than 16 fx4 asm loads in flight --
// the compiler can't see asm outputs as pending loads, so register spills of
// in-flight values silently produce garbage.  Two batches of 16, reused regs.
#define GLD1(x, p) \
  asm volatile("global_load_dwordx4 %0, %1, off sc0 sc1" : "=&v"(x) : "v"(p) : "memory")
#define GLD8(x0,x1,x2,x3,x4,x5,x6,x7,p0,p1,p2,p3,p4,p5,p6,p7) \
  asm volatile( \
    "global_load_dwordx4 %0, %8, off sc0 sc1\n\t" \
    "global_load_dwordx4 %1, %9, off sc0 sc1\n\t" \
    "global_load_dwordx4 %2, %10, off sc0 sc1\n\t" \
    "global_load_dwordx4 %3, %11, off sc0 sc1\n\t" \
    "global_load_dwordx4 %4, %12, off sc0 sc1\n\t" \
    "global_load_dwordx4 %5, %13, off sc0 sc1\n\t" \
    "global_load_dwordx4 %6, %14, off sc0 sc1\n\t" \
    "global_load_dwordx4 %7, %15, off sc0 sc1" \
    : "=&v"(x0),"=&v"(x1),"=&v"(x2),"=&v"(x3), \
      "=&v"(x4),"=&v"(x5),"=&v"(x6),"=&v"(x7) \
    : "v"(p0),"v"(p1),"v"(p2),"v"(p3),"v"(p4),"v"(p5),"v"(p6),"v"(p7) \
    : "memory")
#define VWAIT8(x0,x1,x2,x3,x4,x5,x6,x7) \
  asm volatile("s_waitcnt vmcnt(0)" \
    : "+v"(x0),"+v"(x1),"+v"(x2),"+v"(x3),"+v"(x4),"+v"(x5),"+v"(x6),"+v"(x7) :: "memory")
#define VWAIT11(x0,x1,x2,x3,x4,x5,x6,x7,x8,x9,x10) \
  asm volatile("s_waitcnt vmcnt(0)" \
    : "+v"(x0),"+v"(x1),"+v"(x2),"+v"(x3),"+v"(x4),"+v"(x5), \
      "+v"(x6),"+v"(x7),"+v"(x8),"+v"(x9),"+v"(x10) :: "memory")
#define GST4(p, v) \
  asm volatile("global_store_dwordx4 %0, %1, off sc0 sc1" :: "v"(p), "v"(v) : "memory")

#define BAR_LDS()  asm volatile("s_waitcnt lgkmcnt(0)\n\ts_barrier" ::: "memory")
#define BAR_ONLY() asm volatile("s_barrier" ::: "memory")
#define BAR_FULL() asm volatile("s_waitcnt vmcnt(0) lgkmcnt(0)\n\ts_barrier" ::: "memory")
#define LGKM0()    asm volatile("s_waitcnt lgkmcnt(0)" ::: "memory")

__global__ void __launch_bounds__(256, 1) ring_kernel(
    const float* __restrict__ inbound, const float* __restrict__ Wf,
    const float* __restrict__ bf, const float* __restrict__ Ws,
    const float* __restrict__ bs, float* __restrict__ out,
    unsigned* __restrict__ flags)
{
  __shared__ float T[G*TSZ];    // 4 integral-image tiles, 45.8 KB
  __shared__ fx4   WFS[KC];     // WFS[i][j] = Wf[ch0+j][i]

  const int b    = blockIdx.x;
  const int n    = b >> 5;
  const int cg   = (b >> 2) & (CG-1);
  const int rb   = b & (RB-1);
  const int tid  = threadIdx.x;
  const int lane = tid & 63;
  const int wave = tid >> 6;          // wave w owns tile/channel ch0+w
  const int r0   = rb * RROWS;
  const int ch0  = cg * G;

  const float inh = Ws[0];
  const float exc = Ws[14*29 + 14];
  const float w9  = exc - inh;

  if (tid < KC) {
    fx4 wv;
    wv[0] = Wf[(ch0+0)*KC + tid]; wv[1] = Wf[(ch0+1)*KC + tid];
    wv[2] = Wf[(ch0+2)*KC + tid]; wv[3] = Wf[(ch0+3)*KC + tid];
    WFS[tid] = wv;
  }
  BAR_LDS();

  // thread owns the same spatial fx4 in all 4 channels
  const int off = r0*WW + tid*4;
  const int rl  = tid >> 4;
  const int w0  = (tid & 15) * 4;
  const int br  = rl + HALO;

  fx4 base[G];
  #pragma unroll
  for (int j = 0; j < G; ++j) {
    const float* dp = inbound + (size_t)(n*KC + ch0 + j)*HWSZ + off;
    float bsum = bf[ch0+j] + bs[ch0+j];
    base[j][0] = 0.5f*dp[0] + bsum; base[j][1] = 0.5f*dp[1] + bsum;
    base[j][2] = 0.5f*dp[2] + bsum; base[j][3] = 0.5f*dp[3] + bsum;
  }

  // stage geometry: wave's tile = 44 rows x 16 fx4 = 704 chunks, 11 per lane
  int  sgofs[11], slofs[11]; bool sval[11];
  #pragma unroll
  for (int q = 0; q < 11; ++q) {
    int id  = lane + 64*q;
    int row = id >> 4;
    int c4  = (id & 15) * 4;
    int g   = r0 - HALO + row;
    sval[q]  = (g >= 0 && g < HH);
    int gc   = g < 0 ? 0 : (g > HH-1 ? HH-1 : g);
    sgofs[q] = gc*WW + c4;
    slofs[q] = row*SW + c4;
  }
  float* Tw = T + wave*TSZ;

  // flags: flag[(n,cg,rb)] == s  <=>  wg finished writing slice s-1.
  const int ownf = ((n<<5) | (cg<<2) | rb) * FLAG_STRIDE;
  int pollf = ownf;
  if (tid < CG)                  pollf = ((n<<5) | (tid<<2) | rb)    * FLAG_STRIDE;
  else if (tid == 8 && rb>0)     pollf = ((n<<5) | (cg<<2) | (rb-1)) * FLAG_STRIDE;
  else if (tid == 9 && rb<RB-1)  pollf = ((n<<5) | (cg<<2) | (rb+1)) * FLAG_STRIDE;
  unsigned* pollp = flags + pollf;
  unsigned* ownp  = flags + ownf;

  fx4 xn[G];                       // persistent state: X[ch0+j][own px]
  #pragma unroll
  for (int j = 0; j < G; ++j) xn[j] = fx4{0.f,0.f,0.f,0.f};

  for (int t = 0; t < TT; ++t) {
    fx4 sf[G], acc[G];
    #pragma unroll
    for (int j = 0; j < G; ++j) { sf[j] = fx4{0,0,0,0}; acc[j] = fx4{0,0,0,0}; }

    if (t > 0) {
      const float* Xprev = out + (size_t)((n*TT + (t-1))*KC)*HWSZ;

      // ---- wait for the 10 producers of slice t-1 ----
      if (tid < 10) {
        const unsigned tgt = (unsigned)t;
        while (__hip_atomic_load(pollp, __ATOMIC_RELAXED, __HIP_MEMORY_SCOPE_AGENT) < tgt) {
          __builtin_amdgcn_s_sleep(1);
        }
      }
      BAR_ONLY();

      fx4 A0,A1,A2,A3,A4,A5,A6,A7, B0,B1,B2,B3,B4,B5,B6,B7;   // <=16 fx4 in flight
      const float* Xp = Xprev + off;

      // ---- stage own tile (wave w -> channel ch0+w), 11 chunks/lane ----
      {
        const float* Xc = Xprev + (size_t)(ch0 + wave)*HWSZ;
        fx4 h0,h1,h2,h3,h4,h5,h6,h7,h8,h9,h10;
        GLD1(h0,(const fx4*)(Xc+sgofs[0]));  GLD1(h1,(const fx4*)(Xc+sgofs[1]));
        GLD1(h2,(const fx4*)(Xc+sgofs[2]));  GLD1(h3,(const fx4*)(Xc+sgofs[3]));
        GLD1(h4,(const fx4*)(Xc+sgofs[4]));  GLD1(h5,(const fx4*)(Xc+sgofs[5]));
        GLD1(h6,(const fx4*)(Xc+sgofs[6]));  GLD1(h7,(const fx4*)(Xc+sgofs[7]));
        GLD1(h8,(const fx4*)(Xc+sgofs[8]));  GLD1(h9,(const fx4*)(Xc+sgofs[9]));
        GLD1(h10,(const fx4*)(Xc+sgofs[10]));
        // batch 1 of matvec rides the same LLC round trip
        GLD8(A0,A1,A2,A3,A4,A5,A6,A7,
          (const fx4*)(Xp+(size_t)0*HWSZ),(const fx4*)(Xp+(size_t)1*HWSZ),
          (const fx4*)(Xp+(size_t)2*HWSZ),(const fx4*)(Xp+(size_t)3*HWSZ),
          (const fx4*)(Xp+(size_t)4*HWSZ),(const fx4*)(Xp+(size_t)5*HWSZ),
          (const fx4*)(Xp+(size_t)6*HWSZ),(const fx4*)(Xp+(size_t)7*HWSZ));
        GLD8(B0,B1,B2,B3,B4,B5,B6,B7,
          (const fx4*)(Xp+(size_t)8*HWSZ),(const fx4*)(Xp+(size_t)9*HWSZ),
          (const fx4*)(Xp+(size_t)10*HWSZ),(const fx4*)(Xp+(size_t)11*HWSZ),
          (const fx4*)(Xp+(size_t)12*HWSZ),(const fx4*)(Xp+(size_t)13*HWSZ),
          (const fx4*)(Xp+(size_t)14*HWSZ),(const fx4*)(Xp+(size_t)15*HWSZ));
        VWAIT11(h0,h1,h2,h3,h4,h5,h6,h7,h8,h9,h10);   // vmcnt(0): drains A,B too (concurrent)
        fx4 hh[11] = {h0,h1,h2,h3,h4,h5,h6,h7,h8,h9,h10};
        #pragma unroll
        for (int q = 0; q < 11; ++q) {
          fx4 v = sval[q] ? hh[q] : fx4{0.f,0.f,0.f,0.f};
          Tw[slofs[q]+0]=v[0]; Tw[slofs[q]+1]=v[1];
          Tw[slofs[q]+2]=v[2]; Tw[slofs[q]+3]=v[3];
        }
      }

      // ---- scans on own tile (same wave: program order + lgkm waits) ----
      if (lane < BROWS) {
        float* Tr = Tw + lane*SW;
        float a = 0.f;
        #pragma unroll 8
        for (int cc = 0; cc < WW; ++cc) { a += Tr[cc]; Tr[cc] = a; }
      }
      LGKM0();
      {
        float* Tc = Tw + lane;
        float a = 0.f;
        #pragma unroll 4
        for (int r = 0; r < BROWS; ++r) { a += Tc[r*SW]; Tc[r*SW] = a; }
      }
      BAR_LDS();                      // all 4 tiles ready for cross-wave reads

      // ---- box fields: own 4 px in each of the 4 tiles ----
      #pragma unroll
      for (int j = 0; j < G; ++j) {
        const float* Tj = T + j*TSZ;
        #pragma unroll
        for (int jj = 0; jj < 4; ++jj) {
          int w = w0 + jj;
          int hi  = br + 14, lo  = br - 15;
          int whi = (w + 14 > 63) ? 63 : (w + 14);
          int wlo = w - 15;
          float b29 = Tj[hi*SW + whi];
          if (wlo >= 0) b29 -= Tj[hi*SW + wlo];
          if (lo  >= 0) { b29 -= Tj[lo*SW + whi]; if (wlo >= 0) b29 += Tj[lo*SW + wlo]; }
          int hi2  = br + 4, lo2 = br - 5;
          int whi2 = (w + 4 > 63) ? 63 : (w + 4);
          int wlo2 = w - 5;
          float b9 = Tj[hi2*SW + whi2];
          if (wlo2 >= 0) b9 -= Tj[hi2*SW + wlo2];
          b9 -= Tj[lo2*SW + whi2];
          if (wlo2 >= 0) b9 += Tj[lo2*SW + wlo2];
          sf[j][jj] = inh*b29 + w9*b9;
        }
      }

      // ---- matvec: two batches of 16 channels, registers reused ----
      #define ACC4(V, i) do { fx4 wv = WFS[i]; \
        acc[0] += wv[0]*(V); acc[1] += wv[1]*(V); \
        acc[2] += wv[2]*(V); acc[3] += wv[3]*(V); } while (0)
      VWAIT8(A0,A1,A2,A3,A4,A5,A6,A7);
      VWAIT8(B0,B1,B2,B3,B4,B5,B6,B7);
      ACC4(A0,0);  ACC4(A1,1);  ACC4(A2,2);  ACC4(A3,3);
      ACC4(A4,4);  ACC4(A5,5);  ACC4(A6,6);  ACC4(A7,7);
      GLD8(A0,A1,A2,A3,A4,A5,A6,A7,
        (const fx4*)(Xp+(size_t)16*HWSZ),(const fx4*)(Xp+(size_t)17*HWSZ),
        (const fx4*)(Xp+(size_t)18*HWSZ),(const fx4*)(Xp+(size_t)19*HWSZ),
        (const fx4*)(Xp+(size_t)20*HWSZ),(const fx4*)(Xp+(size_t)21*HWSZ),
        (const fx4*)(Xp+(size_t)22*HWSZ),(const fx4*)(Xp+(size_t)23*HWSZ));
      ACC4(B0,8);  ACC4(B1,9);  ACC4(B2,10); ACC4(B3,11);
      ACC4(B4,12); ACC4(B5,13); ACC4(B6,14); ACC4(B7,15);
      GLD8(B0,B1,B2,B3,B4,B5,B6,B7,
        (const fx4*)(Xp+(size_t)24*HWSZ),(const fx4*)(Xp+(size_t)25*HWSZ),
        (const fx4*)(Xp+(size_t)26*HWSZ),(const fx4*)(Xp+(size_t)27*HWSZ),
        (const fx4*)(Xp+(size_t)28*HWSZ),(const fx4*)(Xp+(size_t)29*HWSZ),
        (const fx4*)(Xp+(size_t)30*HWSZ),(const fx4*)(Xp+(size_t)31*HWSZ));
      VWAIT8(A0,A1,A2,A3,A4,A5,A6,A7);
      VWAIT8(B0,B1,B2,B3,B4,B5,B6,B7);
      ACC4(A0,16); ACC4(A1,17); ACC4(A2,18); ACC4(A3,19);
      ACC4(A4,20); ACC4(A5,21); ACC4(A6,22); ACC4(A7,23);
      ACC4(B0,24); ACC4(B1,25); ACC4(B2,26); ACC4(B3,27);
      ACC4(B4,28); ACC4(B5,29); ACC4(B6,30); ACC4(B7,31);
      #undef ACC4
    }

    // ---- update (xold = xn in registers) + store ----
    float* ob = out + (size_t)((n*TT + t)*KC)*HWSZ + off;
    #pragma unroll
    for (int j = 0; j < G; ++j) {
      fx4 S = base[j] + sf[j] + acc[j];
      fx4 v;
      v[0] = 0.8f*xn[j][0] + 0.2f*fmaxf(S[0], 0.f);
      v[1] = 0.8f*xn[j][1] + 0.2f*fmaxf(S[1], 0.f);
      v[2] = 0.8f*xn[j][2] + 0.2f*fmaxf(S[2], 0.f);
      v[3] = 0.8f*xn[j][3] + 0.2f*fmaxf(S[3], 0.f);
      xn[j] = v;
      GST4((fx4*)(ob + (size_t)(ch0+j)*HWSZ), v);
    }

    // ---- publish slice t ----
    if (t < TT-1) {
      BAR_FULL();
      if (tid == 0) {
        __hip_atomic_store(ownp, (unsigned)(t+1), __ATOMIC_RELAXED,
                           __HIP_MEMORY_SCOPE_AGENT);
      }
    }
  }
}

extern "C" void kernel_launch(void* const* d_in, const int* in_sizes, int n_in,
                              void* d_out, int out_size, void* d_ws, size_t ws_size,
                              hipStream_t stream) {
  const float* inbound = (const float*)d_in[0];
  const float* Wf      = (const float*)d_in[1];
  const float* bf      = (const float*)d_in[2];
  const float* Ws      = (const float*)d_in[3];
  const float* bs      = (const float*)d_in[4];
  float* out = (float*)d_out;
  unsigned* flags = (unsigned*)d_ws;

  hipMemsetAsync(d_ws, 0, NWG*FLAG_STRIDE*sizeof(unsigned), stream);

  void* args[] = {(void*)&inbound, (void*)&Wf, (void*)&bf, (void*)&Ws,
                  (void*)&bs, (void*)&out, (void*)&flags};
  hipLaunchCooperativeKernel((void*)ring_kernel, dim3(NWG), dim3(256),
                             args, 0, stream);
}